// Round 2
// baseline (265.861 us; speedup 1.0000x reference)
//
#include <hip/hip_runtime.h>
#include <math.h>

#define NB 2048
#define NS 200
#define ND 128
#define NH1 64
#define NH2 32

// LDS layout (float offsets)
#define OFF_W1E   0        // 2 * 8192 (per-batch W1eff [128][64])
#define OFF_W2    16384    // 2048
#define OFF_Q     18432    // 2*128
#define OFF_BIAS  18688    // 2*64
#define OFF_B2    18816    // 32
#define OFF_W3    18848    // 32
#define OFF_SC    18880    // 2*256 raw scores
#define OFF_WB    19392    // 256 softmax weights (per-b, reused sequentially)
#define OFF_WRED  19648    // 8
#define OFF_BPRED 19656    // 260: bias partials (phase0) UNION pass2 partials
#define LDS_FLOATS 19916   // 79664 B -> 2 blocks/CU

extern "C" __global__ void __launch_bounds__(256, 2)
tdra_main(const float* __restrict__ query,
          const float* __restrict__ keys,
          const int*   __restrict__ kmask,
          const float* __restrict__ W1,
          const float* __restrict__ b1,
          const float* __restrict__ a1p,
          const float* __restrict__ W2,
          const float* __restrict__ b2,
          const float* __restrict__ a2p,
          const float* __restrict__ W3,
          const float* __restrict__ b3p,
          float* __restrict__ out)
{
    __shared__ float lds[LDS_FLOATS];
    const int tid = threadIdx.x;
    const int b0  = blockIdx.x * 2;

    const float a1 = a1p[0];
    const float a2 = a2p[0];
    const float b3 = b3p[0];

    // ---------- Phase 0a: stage W2, b2, W3, q(both b) ----------
    {
        float4 v0 = *(const float4*)(W2 + tid * 4);
        float4 v1 = *(const float4*)(W2 + 1024 + tid * 4);
        *(float4*)(lds + OFF_W2 + tid * 4) = v0;
        *(float4*)(lds + OFF_W2 + 1024 + tid * 4) = v1;
    }
    if (tid < 32)                  lds[OFF_B2 + tid] = b2[tid];
    else if (tid < 64)             lds[OFF_W3 + (tid - 32)] = W3[tid - 32];
    else if (tid >= 128 && tid < 192) {
        int bb = (tid - 128) >> 5, i = (tid - 128) & 31;
        float4 qv = *(const float4*)(query + (size_t)(b0 + bb) * ND + i * 4);
        *(float4*)(lds + OFF_Q + bb * 128 + i * 4) = qv;
    }
    __syncthreads();

    // ---------- Phase 0b: W1eff[bb] = W1a + W1d + q*W1c ; bias_eff[bb] ----------
    for (int bb = 0; bb < 2; ++bb) {
        const int wbase = OFF_W1E + (bb << 13);
        #pragma unroll
        for (int i = 0; i < 8; ++i) {
            int e = i * 1024 + tid * 4;        // flat [d][h], 4 at a time (same d)
            int d = e >> 6;
            float qd = lds[OFF_Q + bb * 128 + d];
            float4 va = *(const float4*)(W1 + e);            // rows 0..127   (keys)
            float4 vc = *(const float4*)(W1 + 16384 + e);    // rows 256..383 (k*q)
            float4 vd = *(const float4*)(W1 + 24576 + e);    // rows 384..511 (k-q)
            float4 r;
            r.x = va.x + vd.x + qd * vc.x;
            r.y = va.y + vd.y + qd * vc.y;
            r.z = va.z + vd.z + qd * vc.z;
            r.w = va.w + vd.w + qd * vc.w;
            *(float4*)(lds + wbase + e) = r;
        }
        {
            // bias partials: q @ (W1b - W1d)
            int h = tid & 63, qt = tid >> 6;   // 4 quarters of 32 d
            const float* pb = W1 + (size_t)(128 + qt * 32) * 64 + h;
            const float* pd = W1 + (size_t)(384 + qt * 32) * 64 + h;
            float p = 0.f;
            #pragma unroll 8
            for (int i = 0; i < 32; ++i)
                p = fmaf(lds[OFF_Q + bb * 128 + qt * 32 + i], pb[i * 64] - pd[i * 64], p);
            lds[OFF_BPRED + qt * 65 + h] = p;
        }
        __syncthreads();
        if (tid < 64) {
            lds[OFF_BIAS + bb * 64 + tid] = b1[tid]
                + lds[OFF_BPRED + tid]       + lds[OFF_BPRED + 65 + tid]
                + lds[OFF_BPRED + 130 + tid] + lds[OFF_BPRED + 195 + tid];
        }
        __syncthreads();
    }

    // ---------- Main compute: each thread owns 2 s-rows of one b ----------
    const int bb = tid >> 7;          // waves 0,1 -> b0 ; waves 2,3 -> b1
    const int w  = tid & 127;         // worker id; w<100 active (s = 2w, 2w+1)
    const int bme = b0 + bb;
    const int wbase = OFF_W1E + (bb << 13);

    if (w < 100) {
        const float* k0p = keys + ((size_t)bme * NS + 2 * w) * ND;
        const float* k1p = k0p + ND;

        float acc[128];               // [0..63]=h1(s0), [64..127]=h1(s1)
        #pragma unroll
        for (int i = 0; i < 128; ++i) acc[i] = 0.f;

        #pragma unroll 1
        for (int dt = 0; dt < 128; dt += 8) {
            float4 ka0 = *(const float4*)(k0p + dt);
            float4 ka1 = *(const float4*)(k0p + dt + 4);
            float4 kb0 = *(const float4*)(k1p + dt);
            float4 kb1 = *(const float4*)(k1p + dt + 4);
            float k0r[8] = {ka0.x, ka0.y, ka0.z, ka0.w, ka1.x, ka1.y, ka1.z, ka1.w};
            float k1r[8] = {kb0.x, kb0.y, kb0.z, kb0.w, kb1.x, kb1.y, kb1.z, kb1.w};
            #pragma unroll
            for (int dd = 0; dd < 8; ++dd) {
                #pragma unroll
                for (int hq = 0; hq < 16; ++hq) {
                    float4 wv = *(const float4*)(lds + wbase + (dt + dd) * 64 + 4 * hq);
                    acc[hq * 4 + 0] = fmaf(k0r[dd], wv.x, acc[hq * 4 + 0]);
                    acc[hq * 4 + 1] = fmaf(k0r[dd], wv.y, acc[hq * 4 + 1]);
                    acc[hq * 4 + 2] = fmaf(k0r[dd], wv.z, acc[hq * 4 + 2]);
                    acc[hq * 4 + 3] = fmaf(k0r[dd], wv.w, acc[hq * 4 + 3]);
                    acc[64 + hq * 4 + 0] = fmaf(k1r[dd], wv.x, acc[64 + hq * 4 + 0]);
                    acc[64 + hq * 4 + 1] = fmaf(k1r[dd], wv.y, acc[64 + hq * 4 + 1]);
                    acc[64 + hq * 4 + 2] = fmaf(k1r[dd], wv.z, acc[64 + hq * 4 + 2]);
                    acc[64 + hq * 4 + 3] = fmaf(k1r[dd], wv.w, acc[64 + hq * 4 + 3]);
                }
            }
        }

        // bias + PReLU -> h1 in regs
        #pragma unroll
        for (int h = 0; h < 64; ++h) {
            float bv = lds[OFF_BIAS + bb * 64 + h];
            float v0 = acc[h] + bv;
            acc[h]      = fmaxf(v0, 0.f) + a1 * fminf(v0, 0.f);
            float v1 = acc[64 + h] + bv;
            acc[64 + h] = fmaxf(v1, 0.f) + a1 * fminf(v1, 0.f);
        }

        // GEMM2 + PReLU + W3 dot, scores in regs
        float sc0 = b3, sc1 = b3;
        #pragma unroll 1
        for (int jq = 0; jq < 8; ++jq) {
            float4 bv2 = *(const float4*)(lds + OFF_B2 + 4 * jq);
            float c00 = bv2.x, c01 = bv2.y, c02 = bv2.z, c03 = bv2.w;
            float c10 = bv2.x, c11 = bv2.y, c12 = bv2.z, c13 = bv2.w;
            #pragma unroll
            for (int h = 0; h < 64; ++h) {
                float4 wv = *(const float4*)(lds + OFF_W2 + h * 32 + 4 * jq);
                c00 = fmaf(acc[h], wv.x, c00);
                c01 = fmaf(acc[h], wv.y, c01);
                c02 = fmaf(acc[h], wv.z, c02);
                c03 = fmaf(acc[h], wv.w, c03);
                c10 = fmaf(acc[64 + h], wv.x, c10);
                c11 = fmaf(acc[64 + h], wv.y, c11);
                c12 = fmaf(acc[64 + h], wv.z, c12);
                c13 = fmaf(acc[64 + h], wv.w, c13);
            }
            float4 w3v = *(const float4*)(lds + OFF_W3 + 4 * jq);
            float v;
            v = fmaxf(c00, 0.f) + a2 * fminf(c00, 0.f); sc0 = fmaf(v, w3v.x, sc0);
            v = fmaxf(c01, 0.f) + a2 * fminf(c01, 0.f); sc0 = fmaf(v, w3v.y, sc0);
            v = fmaxf(c02, 0.f) + a2 * fminf(c02, 0.f); sc0 = fmaf(v, w3v.z, sc0);
            v = fmaxf(c03, 0.f) + a2 * fminf(c03, 0.f); sc0 = fmaf(v, w3v.w, sc0);
            v = fmaxf(c10, 0.f) + a2 * fminf(c10, 0.f); sc1 = fmaf(v, w3v.x, sc1);
            v = fmaxf(c11, 0.f) + a2 * fminf(c11, 0.f); sc1 = fmaf(v, w3v.y, sc1);
            v = fmaxf(c12, 0.f) + a2 * fminf(c12, 0.f); sc1 = fmaf(v, w3v.z, sc1);
            v = fmaxf(c13, 0.f) + a2 * fminf(c13, 0.f); sc1 = fmaf(v, w3v.w, sc1);
        }
        lds[OFF_SC + bb * 256 + 2 * w + 0] = sc0;
        lds[OFF_SC + bb * 256 + 2 * w + 1] = sc1;
    }
    __syncthreads();

    // ---------- Epilogue per batch: decay + mask + softmax + pass2 ----------
    const int wid = tid >> 6, lane = tid & 63;
    for (int bbe = 0; bbe < 2; ++bbe) {
        const int bm = b0 + bbe;
        float sc = -INFINITY;
        if (tid < NS) {
            if (kmask[(size_t)bm * NS + tid] != 0)
                sc = lds[OFF_SC + bbe * 256 + tid] * expf(0.1f * (float)(tid - (NS - 1)));
        }
        float m = sc;
        #pragma unroll
        for (int o = 32; o > 0; o >>= 1) m = fmaxf(m, __shfl_xor(m, o, 64));
        if (lane == 0) lds[OFF_WRED + wid] = m;
        __syncthreads();
        float M = fmaxf(fmaxf(lds[OFF_WRED + 0], lds[OFF_WRED + 1]),
                        fmaxf(lds[OFF_WRED + 2], lds[OFF_WRED + 3]));
        float e = 0.f;
        if (tid < NS && M > -INFINITY) e = expf(sc - M);
        float ssum = e;
        #pragma unroll
        for (int o = 32; o > 0; o >>= 1) ssum += __shfl_xor(ssum, o, 64);
        if (lane == 0) lds[OFF_WRED + 4 + wid] = ssum;
        __syncthreads();
        float SUM = lds[OFF_WRED + 4] + lds[OFF_WRED + 5]
                  + lds[OFF_WRED + 6] + lds[OFF_WRED + 7];
        float wv = (SUM > 0.f) ? (e / SUM) : 0.f;
        if (tid < NS) {
            lds[OFF_WB + tid] = wv;
            out[(size_t)NB * ND + (size_t)bm * NS + tid] = wv;
        }
        __syncthreads();

        // pass 2: weighted_sum = w @ keys
        {
            const int d = tid & 127, half = tid >> 7;
            const float* kp = keys + ((size_t)bm * NS + half * 100) * ND + d;
            float pacc = 0.f;
            #pragma unroll 5
            for (int i = 0; i < 100; ++i)
                pacc = fmaf(lds[OFF_WB + half * 100 + i], kp[(size_t)i * ND], pacc);
            lds[OFF_BPRED + half * 128 + d] = pacc;
        }
        __syncthreads();
        if (tid < 128)
            out[(size_t)bm * ND + tid] = lds[OFF_BPRED + tid] + lds[OFF_BPRED + 128 + tid];
        __syncthreads();   // protect WB/WRED/BPRED reuse next iteration
    }
}

extern "C" void kernel_launch(void* const* d_in, const int* in_sizes, int n_in,
                              void* d_out, int out_size, void* d_ws, size_t ws_size,
                              hipStream_t stream) {
    (void)in_sizes; (void)n_in; (void)d_ws; (void)ws_size; (void)out_size;
    const float* query = (const float*)d_in[0];
    const float* keys  = (const float*)d_in[1];
    const int*   kmask = (const int*)d_in[2];
    const float* W1 = (const float*)d_in[3];
    const float* b1 = (const float*)d_in[4];
    const float* a1 = (const float*)d_in[5];
    const float* W2 = (const float*)d_in[6];
    const float* b2 = (const float*)d_in[7];
    const float* a2 = (const float*)d_in[8];
    const float* W3 = (const float*)d_in[9];
    const float* b3 = (const float*)d_in[10];
    float* out = (float*)d_out;

    hipLaunchKernelGGL(tdra_main, dim3(NB / 2), dim3(256), 0, stream,
                       query, keys, kmask, W1, b1, a1, W2, b2, a2, W3, b3, out);
}

// Round 3
// 204.983 us; speedup vs baseline: 1.2970x; 1.2970x over previous
//
#include <hip/hip_runtime.h>
#include <math.h>

#define NB 2048
#define NS 200
#define ND 128

// LDS layout (float offsets)
#define OFF_W1E   0        // 8192  W1eff [128 d][64 h]
#define OFF_W2    8192     // 2048  [64 h][32 j]
#define OFF_Q     10240    // 128
#define OFF_BIAS  10368    // 64
#define OFF_B2    10432    // 32
#define OFF_W3    10464    // 32
#define OFF_WB    10496    // 256 softmax weights
#define OFF_WRED  10752    // 8
#define OFF_BP    10760    // 260: phase0 bias partials UNION pass2 partials (256)
#define LDS_FLOATS 11020   // 44080 B -> 3 blocks/CU

extern "C" __global__ void __launch_bounds__(256, 3)
tdra_main(const float* __restrict__ query,
          const float* __restrict__ keys,
          const int*   __restrict__ kmask,
          const float* __restrict__ W1,
          const float* __restrict__ b1,
          const float* __restrict__ a1p,
          const float* __restrict__ W2,
          const float* __restrict__ b2,
          const float* __restrict__ a2p,
          const float* __restrict__ W3,
          const float* __restrict__ b3p,
          float* __restrict__ out)
{
    __shared__ float lds[LDS_FLOATS];
    const int tid = threadIdx.x;
    const int b   = blockIdx.x;

    const float a1 = a1p[0];
    const float a2 = a2p[0];
    const float b3 = b3p[0];

    // ---------- Phase 0a: stage W2, q, b2, W3 ----------
    {
        float4 v0 = *(const float4*)(W2 + tid * 4);
        float4 v1 = *(const float4*)(W2 + 1024 + tid * 4);
        *(float4*)(lds + OFF_W2 + tid * 4) = v0;
        *(float4*)(lds + OFF_W2 + 1024 + tid * 4) = v1;
    }
    if (tid < 32) {
        float4 qv = *(const float4*)(query + (size_t)b * ND + tid * 4);
        *(float4*)(lds + OFF_Q + tid * 4) = qv;
    } else if (tid < 64) {
        lds[OFF_B2 + (tid - 32)] = b2[tid - 32];
    } else if (tid < 96) {
        lds[OFF_W3 + (tid - 64)] = W3[tid - 64];
    }
    __syncthreads();

    // ---------- Phase 0b: W1eff = W1a + W1d + q*W1c ; bias partials ----------
    #pragma unroll
    for (int i = 0; i < 8; ++i) {
        int e = i * 1024 + tid * 4;        // flat [d][h], 4 at a time (same d)
        int d = e >> 6;
        float qd = lds[OFF_Q + d];
        float4 va = *(const float4*)(W1 + e);            // rows 0..127   (keys)
        float4 vc = *(const float4*)(W1 + 16384 + e);    // rows 256..383 (k*q)
        float4 vd = *(const float4*)(W1 + 24576 + e);    // rows 384..511 (k-q)
        float4 r;
        r.x = va.x + vd.x + qd * vc.x;
        r.y = va.y + vd.y + qd * vc.y;
        r.z = va.z + vd.z + qd * vc.z;
        r.w = va.w + vd.w + qd * vc.w;
        *(float4*)(lds + OFF_W1E + e) = r;
    }
    {
        // bias partials: q @ (W1b - W1d)
        int h = tid & 63, qt = tid >> 6;   // 4 quarters of 32 d
        const float* pb = W1 + (size_t)(128 + qt * 32) * 64 + h;
        const float* pd = W1 + (size_t)(384 + qt * 32) * 64 + h;
        float p = 0.f;
        #pragma unroll 8
        for (int i = 0; i < 32; ++i)
            p = fmaf(lds[OFF_Q + qt * 32 + i], pb[i * 64] - pd[i * 64], p);
        lds[OFF_BP + qt * 65 + h] = p;
    }
    __syncthreads();
    if (tid < 64) {
        lds[OFF_BIAS + tid] = b1[tid]
            + lds[OFF_BP + tid]       + lds[OFF_BP + 65 + tid]
            + lds[OFF_BP + 130 + tid] + lds[OFF_BP + 195 + tid];
    }
    __syncthreads();

    // ---------- Main compute: thread tid owns s-row tid (tid < 200) ----------
    float scval = -INFINITY;
    if (tid < NS) {
        const float* kp = keys + ((size_t)b * NS + tid) * ND;

        float acc[64];
        #pragma unroll
        for (int i = 0; i < 64; ++i) acc[i] = 0.f;

        float4 k0 = *(const float4*)(kp);
        float4 k1 = *(const float4*)(kp + 4);
        #pragma unroll 1
        for (int dt = 0; dt < 128; dt += 8) {
            float kr[8] = {k0.x, k0.y, k0.z, k0.w, k1.x, k1.y, k1.z, k1.w};
            if (dt < 120) {                 // prefetch next 8 d
                k0 = *(const float4*)(kp + dt + 8);
                k1 = *(const float4*)(kp + dt + 12);
            }
            #pragma unroll
            for (int dd = 0; dd < 8; ++dd) {
                #pragma unroll
                for (int hq = 0; hq < 16; ++hq) {
                    float4 wv = *(const float4*)(lds + OFF_W1E + (dt + dd) * 64 + 4 * hq);
                    acc[hq * 4 + 0] = fmaf(kr[dd], wv.x, acc[hq * 4 + 0]);
                    acc[hq * 4 + 1] = fmaf(kr[dd], wv.y, acc[hq * 4 + 1]);
                    acc[hq * 4 + 2] = fmaf(kr[dd], wv.z, acc[hq * 4 + 2]);
                    acc[hq * 4 + 3] = fmaf(kr[dd], wv.w, acc[hq * 4 + 3]);
                }
            }
        }

        // bias + PReLU -> h1 in regs
        #pragma unroll
        for (int h = 0; h < 64; ++h) {
            float v = acc[h] + lds[OFF_BIAS + h];
            acc[h] = fmaxf(v, 0.f) + a1 * fminf(v, 0.f);
        }

        // GEMM2 + PReLU + W3 dot
        float sc = b3;
        #pragma unroll 1
        for (int jq = 0; jq < 8; ++jq) {
            float4 bv2 = *(const float4*)(lds + OFF_B2 + 4 * jq);
            float c0 = bv2.x, c1 = bv2.y, c2 = bv2.z, c3 = bv2.w;
            #pragma unroll
            for (int h = 0; h < 64; ++h) {
                float4 wv = *(const float4*)(lds + OFF_W2 + h * 32 + 4 * jq);
                c0 = fmaf(acc[h], wv.x, c0);
                c1 = fmaf(acc[h], wv.y, c1);
                c2 = fmaf(acc[h], wv.z, c2);
                c3 = fmaf(acc[h], wv.w, c3);
            }
            float4 w3v = *(const float4*)(lds + OFF_W3 + 4 * jq);
            float v;
            v = fmaxf(c0, 0.f) + a2 * fminf(c0, 0.f); sc = fmaf(v, w3v.x, sc);
            v = fmaxf(c1, 0.f) + a2 * fminf(c1, 0.f); sc = fmaf(v, w3v.y, sc);
            v = fmaxf(c2, 0.f) + a2 * fminf(c2, 0.f); sc = fmaf(v, w3v.z, sc);
            v = fmaxf(c3, 0.f) + a2 * fminf(c3, 0.f); sc = fmaf(v, w3v.w, sc);
        }

        // time decay + mask
        if (kmask[(size_t)b * NS + tid] != 0)
            scval = sc * expf(0.1f * (float)(tid - (NS - 1)));
    }

    // ---------- softmax over 200 (all 256 threads participate) ----------
    const int wid = tid >> 6, lane = tid & 63;
    float m = scval;
    #pragma unroll
    for (int o = 32; o > 0; o >>= 1) m = fmaxf(m, __shfl_xor(m, o, 64));
    if (lane == 0) lds[OFF_WRED + wid] = m;
    __syncthreads();
    float M = fmaxf(fmaxf(lds[OFF_WRED + 0], lds[OFF_WRED + 1]),
                    fmaxf(lds[OFF_WRED + 2], lds[OFF_WRED + 3]));
    float e = (M > -INFINITY) ? expf(scval - M) : 0.f;   // scval=-inf -> 0
    float ssum = e;
    #pragma unroll
    for (int o = 32; o > 0; o >>= 1) ssum += __shfl_xor(ssum, o, 64);
    if (lane == 0) lds[OFF_WRED + 4 + wid] = ssum;
    __syncthreads();
    float SUM = lds[OFF_WRED + 4] + lds[OFF_WRED + 5]
              + lds[OFF_WRED + 6] + lds[OFF_WRED + 7];
    float wv = (SUM > 0.f) ? (e / SUM) : 0.f;
    if (tid < NS) {
        lds[OFF_WB + tid] = wv;
        out[(size_t)NB * ND + (size_t)b * NS + tid] = wv;
    }
    __syncthreads();

    // ---------- pass 2: weighted_sum = w @ keys (coalesced) ----------
    {
        const int d = tid & 127, half = tid >> 7;
        const float* kp = keys + ((size_t)b * NS + half * 100) * ND + d;
        float pacc = 0.f;
        #pragma unroll 5
        for (int i = 0; i < 100; ++i)
            pacc = fmaf(lds[OFF_WB + half * 100 + i], kp[(size_t)i * ND], pacc);
        lds[OFF_BP + half * 128 + d] = pacc;
    }
    __syncthreads();
    if (tid < 128)
        out[(size_t)b * ND + tid] = lds[OFF_BP + tid] + lds[OFF_BP + 128 + tid];
}

extern "C" void kernel_launch(void* const* d_in, const int* in_sizes, int n_in,
                              void* d_out, int out_size, void* d_ws, size_t ws_size,
                              hipStream_t stream) {
    (void)in_sizes; (void)n_in; (void)d_ws; (void)ws_size; (void)out_size;
    const float* query = (const float*)d_in[0];
    const float* keys  = (const float*)d_in[1];
    const int*   kmask = (const int*)d_in[2];
    const float* W1 = (const float*)d_in[3];
    const float* b1 = (const float*)d_in[4];
    const float* a1 = (const float*)d_in[5];
    const float* W2 = (const float*)d_in[6];
    const float* b2 = (const float*)d_in[7];
    const float* a2 = (const float*)d_in[8];
    const float* W3 = (const float*)d_in[9];
    const float* b3 = (const float*)d_in[10];
    float* out = (float*)d_out;

    hipLaunchKernelGGL(tdra_main, dim3(NB), dim3(256), 0, stream,
                       query, keys, kmask, W1, b1, a1, W2, b2, a2, W3, b3, out);
}

// Round 4
// 114.187 us; speedup vs baseline: 2.3283x; 1.7952x over previous
//
#include <hip/hip_runtime.h>
#include <math.h>

#define NB 2048
#define NS 200
#define ND 128

typedef __attribute__((ext_vector_type(8))) short bf16x8;
typedef __attribute__((ext_vector_type(4))) float f32x4;

// LDS layout (u32 units)
#define U_W1B   0                       // [128][66] u32 packed hi|lo<<16 = 8448
#define U_W2B   8448                    // [64][34] u32 = 2176
#define U_H1B   10624                   // [208][66] u16 = 13728 u16 = 6864 u32
#define U_Q     17488                   // 128 f32
#define U_BIAS  17616                   // 64 f32
#define U_B2    17680                   // 32 f32
#define U_W3    17712                   // 32 f32
#define U_SC    17744                   // 208 f32
#define U_WB    17952                   // 208 f32
#define U_WRED  18160                   // 8 f32
#define U_BP    18168                   // 260 f32 (bias partials / pass2 partials)
#define U_TOTAL 18428                   // 73712 B -> 2 blocks/CU

extern "C" __global__ void __launch_bounds__(256, 2)
tdra_main(const float* __restrict__ query,
          const float* __restrict__ keys,
          const int*   __restrict__ kmask,
          const float* __restrict__ W1,
          const float* __restrict__ b1,
          const float* __restrict__ a1p,
          const float* __restrict__ W2,
          const float* __restrict__ b2,
          const float* __restrict__ a2p,
          const float* __restrict__ W3,
          const float* __restrict__ b3p,
          float* __restrict__ out)
{
    __shared__ __align__(16) unsigned int smem[U_TOTAL];
    unsigned int*   W1b = smem + U_W1B;
    unsigned int*   W2b = smem + U_W2B;
    unsigned short* h1b = (unsigned short*)(smem + U_H1B);
    float* qf    = (float*)(smem + U_Q);
    float* biasE = (float*)(smem + U_BIAS);
    float* b2f   = (float*)(smem + U_B2);
    float* w3f   = (float*)(smem + U_W3);
    float* scf   = (float*)(smem + U_SC);
    float* wbf   = (float*)(smem + U_WB);
    float* wred  = (float*)(smem + U_WRED);
    float* bpf   = (float*)(smem + U_BP);

    const int tid = threadIdx.x;
    const int b   = blockIdx.x;
    const float a1 = a1p[0];
    const float a2 = a2p[0];
    const float b3 = b3p[0];

    // split f32 -> bf16 hi (truncate) | bf16 lo (truncate of residual), packed u32
    auto packsplit = [](float x) -> unsigned int {
        unsigned int u  = __float_as_uint(x);
        unsigned int hb = u >> 16;
        float lof = x - __uint_as_float(hb << 16);
        unsigned int lb = __float_as_uint(lof) >> 16;
        return hb | (lb << 16);
    };

    // ---------- Phase 0a: q, b2, W3, W2b ----------
    {   // W2b: thread t -> row h=t>>2, cols j0=(t&3)*8
        int h = tid >> 2, j0 = (tid & 3) * 8;
        float4 wa = *(const float4*)(W2 + h * 32 + j0);
        float4 wb = *(const float4*)(W2 + h * 32 + j0 + 4);
        unsigned int* dst = W2b + h * 34 + j0;
        dst[0] = packsplit(wa.x); dst[1] = packsplit(wa.y);
        dst[2] = packsplit(wa.z); dst[3] = packsplit(wa.w);
        dst[4] = packsplit(wb.x); dst[5] = packsplit(wb.y);
        dst[6] = packsplit(wb.z); dst[7] = packsplit(wb.w);
    }
    if (tid < 32) {
        float4 qv = *(const float4*)(query + (size_t)b * ND + tid * 4);
        *(float4*)(qf + tid * 4) = qv;
    } else if (tid < 64) {
        b2f[tid - 32] = b2[tid - 32];
    } else if (tid < 96) {
        w3f[tid - 64] = W3[tid - 64];
    }
    __syncthreads();

    // ---------- Phase 0b: W1b = split(W1a + W1d + q*W1c); bias partials ----------
    #pragma unroll
    for (int i = 0; i < 8; ++i) {
        int e = i * 1024 + tid * 4;        // flat [d][h], 4 elems same d
        int d = e >> 6, h4 = e & 63;
        float qd = qf[d];
        float4 va = *(const float4*)(W1 + e);
        float4 vc = *(const float4*)(W1 + 16384 + e);
        float4 vd = *(const float4*)(W1 + 24576 + e);
        unsigned int* dst = W1b + d * 66 + h4;
        dst[0] = packsplit(va.x + vd.x + qd * vc.x);
        dst[1] = packsplit(va.y + vd.y + qd * vc.y);
        dst[2] = packsplit(va.z + vd.z + qd * vc.z);
        dst[3] = packsplit(va.w + vd.w + qd * vc.w);
    }
    {   // bias partials: q @ (W1b' - W1d)
        int h = tid & 63, qt = tid >> 6;
        const float* pb = W1 + (size_t)(128 + qt * 32) * 64 + h;
        const float* pd = W1 + (size_t)(384 + qt * 32) * 64 + h;
        float p = 0.f;
        #pragma unroll 8
        for (int i = 0; i < 32; ++i)
            p = fmaf(qf[qt * 32 + i], pb[i * 64] - pd[i * 64], p);
        bpf[qt * 65 + h] = p;
    }
    __syncthreads();
    if (tid < 64)
        biasE[tid] = b1[tid] + bpf[tid] + bpf[65 + tid] + bpf[130 + tid] + bpf[195 + tid];
    __syncthreads();

    // ---------- GEMM1 via MFMA: 13 M-tiles over 4 waves ----------
    const int wv = tid >> 6, hl = tid & 15, g = (tid & 63) >> 4;

    f32x4 acc1[4][4];
    #pragma unroll
    for (int i = 0; i < 4; ++i)
        #pragma unroll
        for (int nt = 0; nt < 4; ++nt)
            acc1[i][nt] = (f32x4){0.f, 0.f, 0.f, 0.f};

    #pragma unroll 2
    for (int kk = 0; kk < 4; ++kk) {
        bf16x8 Bh[4], Bl[4];
        #pragma unroll
        for (int nt = 0; nt < 4; ++nt) {
            const unsigned int* wp = W1b + (kk * 32 + 8 * g) * 66 + nt * 16 + hl;
            #pragma unroll
            for (int bb = 0; bb < 8; ++bb) {
                unsigned int wbits = wp[bb * 66];
                Bh[nt][bb] = (short)wbits;
                Bl[nt][bb] = (short)(wbits >> 16);
            }
        }
        #pragma unroll
        for (int i = 0; i < 4; ++i) {
            int mt = wv + 4 * i;
            if (mt < 13) {
                int row = mt * 16 + hl; row = row < 200 ? row : 199;
                const float* ap = keys + ((size_t)b * NS + row) * ND + kk * 32 + 8 * g;
                float4 x0 = *(const float4*)ap;
                float4 x1 = *(const float4*)(ap + 4);
                float xs[8] = {x0.x, x0.y, x0.z, x0.w, x1.x, x1.y, x1.z, x1.w};
                bf16x8 Ah, Al;
                #pragma unroll
                for (int e = 0; e < 8; ++e) {
                    unsigned int u = __float_as_uint(xs[e]);
                    unsigned int hb = u >> 16;
                    float lof = xs[e] - __uint_as_float(hb << 16);
                    Ah[e] = (short)hb;
                    Al[e] = (short)(__float_as_uint(lof) >> 16);
                }
                #pragma unroll
                for (int nt = 0; nt < 4; ++nt)
                    acc1[i][nt] = __builtin_amdgcn_mfma_f32_16x16x32_bf16(Ah, Bh[nt], acc1[i][nt], 0, 0, 0);
                #pragma unroll
                for (int nt = 0; nt < 4; ++nt)
                    acc1[i][nt] = __builtin_amdgcn_mfma_f32_16x16x32_bf16(Ah, Bl[nt], acc1[i][nt], 0, 0, 0);
                #pragma unroll
                for (int nt = 0; nt < 4; ++nt)
                    acc1[i][nt] = __builtin_amdgcn_mfma_f32_16x16x32_bf16(Al, Bh[nt], acc1[i][nt], 0, 0, 0);
            }
        }
    }

    // bias + PReLU -> h1f regs; write hi bf16 to h1b
    float bias_v[4];
    #pragma unroll
    for (int nt = 0; nt < 4; ++nt) bias_v[nt] = biasE[nt * 16 + hl];
    float h1f[4][4][4];
    #pragma unroll
    for (int i = 0; i < 4; ++i) {
        int mt = wv + 4 * i;
        if (mt < 13) {
            #pragma unroll
            for (int nt = 0; nt < 4; ++nt)
                #pragma unroll
                for (int r = 0; r < 4; ++r) {
                    float v = acc1[i][nt][r] + bias_v[nt];
                    h1f[i][nt][r] = fmaxf(v, 0.f) + a1 * fminf(v, 0.f);
                    int m = mt * 16 + 4 * g + r;
                    h1b[m * 66 + nt * 16 + hl] =
                        (unsigned short)(__float_as_uint(h1f[i][nt][r]) >> 16);
                }
        }
    }
    __syncthreads();

    // ---------- GEMM2 via MFMA ----------
    bf16x8 B2h[2][2], B2l[2][2];
    #pragma unroll
    for (int kk2 = 0; kk2 < 2; ++kk2)
        #pragma unroll
        for (int nt2 = 0; nt2 < 2; ++nt2) {
            const unsigned int* wp = W2b + (kk2 * 32 + 8 * g) * 34 + nt2 * 16 + hl;
            #pragma unroll
            for (int bb = 0; bb < 8; ++bb) {
                unsigned int wbits = wp[bb * 34];
                B2h[kk2][nt2][bb] = (short)wbits;
                B2l[kk2][nt2][bb] = (short)(wbits >> 16);
            }
        }

    f32x4 acc2[4][2];
    #pragma unroll
    for (int i = 0; i < 4; ++i) {
        acc2[i][0] = (f32x4){0.f, 0.f, 0.f, 0.f};
        acc2[i][1] = (f32x4){0.f, 0.f, 0.f, 0.f};
    }

    bf16x8 Ah2[4][2];
    #pragma unroll
    for (int i = 0; i < 4; ++i) {
        int mt = wv + 4 * i;
        if (mt < 13) {
            #pragma unroll
            for (int kk2 = 0; kk2 < 2; ++kk2) {
                const unsigned int* hp = (const unsigned int*)h1b
                    + 33 * (mt * 16 + hl) + 16 * kk2 + 4 * g;
                unsigned int w0 = hp[0], w1 = hp[1], w2_ = hp[2], w3_ = hp[3];
                Ah2[i][kk2] = (bf16x8){(short)w0, (short)(w0 >> 16),
                                       (short)w1, (short)(w1 >> 16),
                                       (short)w2_, (short)(w2_ >> 16),
                                       (short)w3_, (short)(w3_ >> 16)};
            }
        }
    }
    #pragma unroll
    for (int kk2 = 0; kk2 < 2; ++kk2)
        #pragma unroll
        for (int i = 0; i < 4; ++i)
            if (wv + 4 * i < 13) {
                #pragma unroll
                for (int nt2 = 0; nt2 < 2; ++nt2)
                    acc2[i][nt2] = __builtin_amdgcn_mfma_f32_16x16x32_bf16(Ah2[i][kk2], B2h[kk2][nt2], acc2[i][nt2], 0, 0, 0);
            }
    #pragma unroll
    for (int kk2 = 0; kk2 < 2; ++kk2)
        #pragma unroll
        for (int i = 0; i < 4; ++i)
            if (wv + 4 * i < 13) {
                #pragma unroll
                for (int nt2 = 0; nt2 < 2; ++nt2)
                    acc2[i][nt2] = __builtin_amdgcn_mfma_f32_16x16x32_bf16(Ah2[i][kk2], B2l[kk2][nt2], acc2[i][nt2], 0, 0, 0);
            }
    __syncthreads();

    // lo pass: overwrite h1b with lo residual
    #pragma unroll
    for (int i = 0; i < 4; ++i) {
        int mt = wv + 4 * i;
        if (mt < 13) {
            #pragma unroll
            for (int nt = 0; nt < 4; ++nt)
                #pragma unroll
                for (int r = 0; r < 4; ++r) {
                    float hf = h1f[i][nt][r];
                    unsigned int hb = __float_as_uint(hf) >> 16;
                    float lof = hf - __uint_as_float(hb << 16);
                    int m = mt * 16 + 4 * g + r;
                    h1b[m * 66 + nt * 16 + hl] =
                        (unsigned short)(__float_as_uint(lof) >> 16);
                }
        }
    }
    __syncthreads();
    #pragma unroll
    for (int i = 0; i < 4; ++i) {
        int mt = wv + 4 * i;
        if (mt < 13) {
            #pragma unroll
            for (int kk2 = 0; kk2 < 2; ++kk2) {
                const unsigned int* hp = (const unsigned int*)h1b
                    + 33 * (mt * 16 + hl) + 16 * kk2 + 4 * g;
                unsigned int w0 = hp[0], w1 = hp[1], w2_ = hp[2], w3_ = hp[3];
                bf16x8 Al2 = (bf16x8){(short)w0, (short)(w0 >> 16),
                                      (short)w1, (short)(w1 >> 16),
                                      (short)w2_, (short)(w2_ >> 16),
                                      (short)w3_, (short)(w3_ >> 16)};
                #pragma unroll
                for (int nt2 = 0; nt2 < 2; ++nt2)
                    acc2[i][nt2] = __builtin_amdgcn_mfma_f32_16x16x32_bf16(Al2, B2h[kk2][nt2], acc2[i][nt2], 0, 0, 0);
            }
        }
    }

    // ---------- scores: b2 + PReLU + W3-dot + cross-lane reduce ----------
    float b2v[2] = {b2f[hl], b2f[16 + hl]};
    float w3v[2] = {w3f[hl], w3f[16 + hl]};
    #pragma unroll
    for (int i = 0; i < 4; ++i) {
        int mt = wv + 4 * i;
        if (mt < 13) {
            #pragma unroll
            for (int r = 0; r < 4; ++r) {
                float v0 = acc2[i][0][r] + b2v[0];
                v0 = fmaxf(v0, 0.f) + a2 * fminf(v0, 0.f);
                float v1 = acc2[i][1][r] + b2v[1];
                v1 = fmaxf(v1, 0.f) + a2 * fminf(v1, 0.f);
                float sv = v0 * w3v[0] + v1 * w3v[1];
                sv += __shfl_xor(sv, 1, 64);
                sv += __shfl_xor(sv, 2, 64);
                sv += __shfl_xor(sv, 4, 64);
                sv += __shfl_xor(sv, 8, 64);
                int m = mt * 16 + 4 * g + r;
                if (hl == 0 && m < 200) scf[m] = sv + b3;
            }
        }
    }
    __syncthreads();

    // ---------- decay + mask + softmax ----------
    float scval = -INFINITY;
    if (tid < NS) {
        if (kmask[(size_t)b * NS + tid] != 0)
            scval = scf[tid] * expf(0.1f * (float)(tid - (NS - 1)));
    }
    const int wid = tid >> 6, lane = tid & 63;
    float mx = scval;
    #pragma unroll
    for (int o = 32; o > 0; o >>= 1) mx = fmaxf(mx, __shfl_xor(mx, o, 64));
    if (lane == 0) wred[wid] = mx;
    __syncthreads();
    float M = fmaxf(fmaxf(wred[0], wred[1]), fmaxf(wred[2], wred[3]));
    float e = (M > -INFINITY) ? expf(scval - M) : 0.f;
    float ssum = e;
    #pragma unroll
    for (int o = 32; o > 0; o >>= 1) ssum += __shfl_xor(ssum, o, 64);
    if (lane == 0) wred[4 + wid] = ssum;
    __syncthreads();
    float SUM = wred[4] + wred[5] + wred[6] + wred[7];
    float wv_ = (SUM > 0.f) ? (e / SUM) : 0.f;
    if (tid < NS) {
        wbf[tid] = wv_;
        out[(size_t)NB * ND + (size_t)b * NS + tid] = wv_;
    }
    __syncthreads();

    // ---------- pass 2: weighted_sum = w @ keys ----------
    {
        const int d = tid & 127, half = tid >> 7;
        const float* kp = keys + ((size_t)b * NS + half * 100) * ND + d;
        float pacc = 0.f;
        #pragma unroll 5
        for (int i = 0; i < 100; ++i)
            pacc = fmaf(wbf[half * 100 + i], kp[(size_t)i * ND], pacc);
        bpf[half * 128 + d] = pacc;
    }
    __syncthreads();
    if (tid < 128)
        out[(size_t)b * ND + tid] = bpf[tid] + bpf[128 + tid];
}

extern "C" void kernel_launch(void* const* d_in, const int* in_sizes, int n_in,
                              void* d_out, int out_size, void* d_ws, size_t ws_size,
                              hipStream_t stream) {
    (void)in_sizes; (void)n_in; (void)d_ws; (void)ws_size; (void)out_size;
    const float* query = (const float*)d_in[0];
    const float* keys  = (const float*)d_in[1];
    const int*   kmask = (const int*)d_in[2];
    const float* W1 = (const float*)d_in[3];
    const float* b1 = (const float*)d_in[4];
    const float* a1 = (const float*)d_in[5];
    const float* W2 = (const float*)d_in[6];
    const float* b2 = (const float*)d_in[7];
    const float* a2 = (const float*)d_in[8];
    const float* W3 = (const float*)d_in[9];
    const float* b3 = (const float*)d_in[10];
    float* out = (float*)d_out;

    hipLaunchKernelGGL(tdra_main, dim3(NB), dim3(256), 0, stream,
                       query, keys, kmask, W1, b1, a1, W2, b2, a2, W3, b3, out);
}

// Round 5
// 83.937 us; speedup vs baseline: 3.1674x; 1.3604x over previous
//
#include <hip/hip_runtime.h>
#include <math.h>

#define NB 2048
#define NS 200
#define ND 128

typedef __attribute__((ext_vector_type(8))) short bf16x8;
typedef __attribute__((ext_vector_type(4))) float f32x4;

// LDS layout (u32 units)
#define U_W1T   0                  // [64 h][132 d] u32 packed hi|lo<<16 = 8448
#define U_W2T   8448               // [32 j][68 h] u32 packed = 2176
#define U_Q     10624              // 128 f32
#define U_BIAS  10752              // 64 f32
#define U_B2    10816              // 32 f32
#define U_W3    10848              // 32 f32
#define U_SC    10880              // 208 f32
#define U_WB    11088              // 208 f32
#define U_WRED  11296              // 8 f32
#define U_BP    11304              // 260 f32
#define U_TOTAL 11564              // 46256 B -> 3 blocks/CU

__device__ __forceinline__ unsigned int packsplit(float x) {
    unsigned int u  = __float_as_uint(x);
    unsigned int hb = u >> 16;
    float lof = x - __uint_as_float(hb << 16);
    return hb | (__float_as_uint(lof) & 0xFFFF0000u);
}

extern "C" __global__ void __launch_bounds__(256, 3)
tdra_main(const float* __restrict__ query,
          const float* __restrict__ keys,
          const int*   __restrict__ kmask,
          const float* __restrict__ W1,
          const float* __restrict__ b1,
          const float* __restrict__ a1p,
          const float* __restrict__ W2,
          const float* __restrict__ b2,
          const float* __restrict__ a2p,
          const float* __restrict__ W3,
          const float* __restrict__ b3p,
          float* __restrict__ out)
{
    __shared__ __align__(16) unsigned int smem[U_TOTAL];
    unsigned int* W1T = smem + U_W1T;
    unsigned int* W2T = smem + U_W2T;
    float* qf    = (float*)(smem + U_Q);
    float* biasE = (float*)(smem + U_BIAS);
    float* b2f   = (float*)(smem + U_B2);
    float* w3f   = (float*)(smem + U_W3);
    float* scf   = (float*)(smem + U_SC);
    float* wbf   = (float*)(smem + U_WB);
    float* wred  = (float*)(smem + U_WRED);
    float* bpf   = (float*)(smem + U_BP);

    const int tid = threadIdx.x;
    const int b   = blockIdx.x;
    const float a1 = a1p[0];
    const float a2 = a2p[0];
    const float b3 = b3p[0];

    // ---------- Phase 0a: q, b2, W3 staging + W2T build ----------
    if (tid < 32) {
        float4 qv = *(const float4*)(query + (size_t)b * ND + tid * 4);
        *(float4*)(qf + tid * 4) = qv;
    } else if (tid < 64) {
        b2f[tid - 32] = b2[tid - 32];
    } else if (tid < 96) {
        w3f[tid - 64] = W3[tid - 64];
    }
    {   // W2T[j][h]: j = tid&31, h-block = tid>>5 (8 h each)
        int j = tid & 31, hblk = tid >> 5;
        unsigned int pk[8];
        #pragma unroll
        for (int i = 0; i < 8; ++i)
            pk[i] = packsplit(W2[(hblk * 8 + i) * 32 + j]);
        unsigned int* dst = W2T + j * 68 + hblk * 8;
        *(uint4*)(dst)     = make_uint4(pk[0], pk[1], pk[2], pk[3]);
        *(uint4*)(dst + 4) = make_uint4(pk[4], pk[5], pk[6], pk[7]);
    }
    __syncthreads();

    // ---------- Phase 0b: W1T[h][d] = split(W1a+W1d+q*W1c); bias partials ----
    {
        int h = tid & 63, dg = tid >> 6;       // wave dg handles dblk dg*8..dg*8+7
        #pragma unroll 2
        for (int i = 0; i < 8; ++i) {
            int dblk = dg * 8 + i;
            unsigned int pk[4];
            #pragma unroll
            for (int jj = 0; jj < 4; ++jj) {
                int d = dblk * 4 + jj;
                float qd = qf[d];
                float va = W1[d * 64 + h];
                float vc = W1[16384 + d * 64 + h];
                float vd = W1[24576 + d * 64 + h];
                pk[jj] = packsplit(va + vd + qd * vc);
            }
            *(uint4*)(W1T + h * 132 + dblk * 4) = make_uint4(pk[0], pk[1], pk[2], pk[3]);
        }
        // bias partials: q @ (W1b - W1d)
        int qt = dg;
        const float* pb = W1 + (size_t)(128 + qt * 32) * 64 + h;
        const float* pd = W1 + (size_t)(384 + qt * 32) * 64 + h;
        float p = 0.f;
        #pragma unroll 8
        for (int i = 0; i < 32; ++i)
            p = fmaf(qf[qt * 32 + i], pb[i * 64] - pd[i * 64], p);
        bpf[qt * 65 + h] = p;
    }
    __syncthreads();
    if (tid < 64)
        biasE[tid] = b1[tid] + bpf[tid] + bpf[65 + tid] + bpf[130 + tid] + bpf[195 + tid];
    __syncthreads();

    // ---------- Main: wave wv owns s-tiles st = wv, wv+4, wv+8, (wv+12) ------
    const int wv = tid >> 6;
    const int c  = tid & 15;
    const int G  = (tid >> 4) & 3;

    // A2 = W2^T fragments, held in regs (st-invariant)
    bf16x8 A2h[2][2], A2l[2][2];
    #pragma unroll
    for (int jt = 0; jt < 2; ++jt)
        #pragma unroll
        for (int kt = 0; kt < 2; ++kt) {
            const unsigned int* p2 = W2T + (jt * 16 + c) * 68 + kt * 32 + 8 * G;
            uint4 wa = *(const uint4*)p2;
            uint4 wb = *(const uint4*)(p2 + 4);
            unsigned int ww[8] = {wa.x, wa.y, wa.z, wa.w, wb.x, wb.y, wb.z, wb.w};
            #pragma unroll
            for (int e = 0; e < 8; ++e) {
                A2h[jt][kt][e] = (short)(ww[e] & 0xFFFFu);
                A2l[jt][kt][e] = (short)(ww[e] >> 16);
            }
        }

    float4 xs[8];                       // keys f32 for current tile
    {
        int row = wv * 16 + c; if (row > 199) row = 199;
        const float* kp = keys + ((size_t)b * NS + row) * ND + 8 * G;
        #pragma unroll
        for (int dt = 0; dt < 4; ++dt) {
            xs[2 * dt]     = *(const float4*)(kp + dt * 32);
            xs[2 * dt + 1] = *(const float4*)(kp + dt * 32 + 4);
        }
    }

    #pragma unroll 1
    for (int st = wv; st < 13; st += 4) {
        // convert keys f32 -> B1 hi/lo frags
        bf16x8 B1h[4], B1l[4];
        #pragma unroll
        for (int dt = 0; dt < 4; ++dt) {
            float t_[8] = {xs[2*dt].x, xs[2*dt].y, xs[2*dt].z, xs[2*dt].w,
                           xs[2*dt+1].x, xs[2*dt+1].y, xs[2*dt+1].z, xs[2*dt+1].w};
            #pragma unroll
            for (int e = 0; e < 8; ++e) {
                unsigned int u  = __float_as_uint(t_[e]);
                unsigned int hb = u >> 16;
                float lof = t_[e] - __uint_as_float(hb << 16);
                B1h[dt][e] = (short)hb;
                B1l[dt][e] = (short)(__float_as_uint(lof) >> 16);
            }
        }
        // prefetch next tile's keys
        if (st + 4 < 13) {
            int row = (st + 4) * 16 + c; if (row > 199) row = 199;
            const float* kp = keys + ((size_t)b * NS + row) * ND + 8 * G;
            #pragma unroll
            for (int dt = 0; dt < 4; ++dt) {
                xs[2 * dt]     = *(const float4*)(kp + dt * 32);
                xs[2 * dt + 1] = *(const float4*)(kp + dt * 32 + 4);
            }
        }

        // GEMM1': acc1[ht] = bias + W1eff^T x K^T
        f32x4 acc1[4];
        #pragma unroll
        for (int ht = 0; ht < 4; ++ht)
            acc1[ht] = *(const f32x4*)(biasE + 16 * ht + 4 * G);
        #pragma unroll
        for (int dt = 0; dt < 4; ++dt) {
            #pragma unroll
            for (int ht = 0; ht < 4; ++ht) {
                const unsigned int* pa = W1T + (16 * ht + c) * 132 + dt * 32 + 8 * G;
                uint4 wa = *(const uint4*)pa;
                uint4 wb = *(const uint4*)(pa + 4);
                unsigned int ww[8] = {wa.x, wa.y, wa.z, wa.w, wb.x, wb.y, wb.z, wb.w};
                bf16x8 A1h, A1l;
                #pragma unroll
                for (int e = 0; e < 8; ++e) {
                    A1h[e] = (short)(ww[e] & 0xFFFFu);
                    A1l[e] = (short)(ww[e] >> 16);
                }
                acc1[ht] = __builtin_amdgcn_mfma_f32_16x16x32_bf16(A1h, B1h[dt], acc1[ht], 0, 0, 0);
                acc1[ht] = __builtin_amdgcn_mfma_f32_16x16x32_bf16(A1h, B1l[dt], acc1[ht], 0, 0, 0);
                acc1[ht] = __builtin_amdgcn_mfma_f32_16x16x32_bf16(A1l, B1h[dt], acc1[ht], 0, 0, 0);
            }
        }

        // PReLU -> packed hi|lo h1
        unsigned int p[4][4];
        #pragma unroll
        for (int ht = 0; ht < 4; ++ht)
            #pragma unroll
            for (int r = 0; r < 4; ++r) {
                float v = acc1[ht][r];
                v = fmaxf(v, 0.f) + a1 * fminf(v, 0.f);
                p[ht][r] = packsplit(v);
            }

        // GEMM2': shfl-transpose h1 into B2 frags; acc2 init with b2
        f32x4 acc2[2];
        acc2[0] = *(const f32x4*)(b2f + 4 * G);
        acc2[1] = *(const f32x4*)(b2f + 16 + 4 * G);
        const int srcbase = ((tid & 16) ? 32 : 0) + c;
        #pragma unroll
        for (int kt = 0; kt < 2; ++kt) {
            unsigned int q[8];
            #pragma unroll
            for (int half = 0; half < 2; ++half) {
                int src = srcbase + half * 16;
                #pragma unroll
                for (int r = 0; r < 4; ++r) {
                    unsigned int v0 = (unsigned int)__shfl((int)p[2 * kt][r], src, 64);
                    unsigned int v1 = (unsigned int)__shfl((int)p[2 * kt + 1][r], src, 64);
                    q[half * 4 + r] = (tid & 32) ? v1 : v0;
                }
            }
            bf16x8 B2h_, B2l_;
            #pragma unroll
            for (int e = 0; e < 8; ++e) {
                B2h_[e] = (short)(q[e] & 0xFFFFu);
                B2l_[e] = (short)(q[e] >> 16);
            }
            #pragma unroll
            for (int jt = 0; jt < 2; ++jt) {
                acc2[jt] = __builtin_amdgcn_mfma_f32_16x16x32_bf16(A2h[jt][kt], B2h_, acc2[jt], 0, 0, 0);
                acc2[jt] = __builtin_amdgcn_mfma_f32_16x16x32_bf16(A2h[jt][kt], B2l_, acc2[jt], 0, 0, 0);
                acc2[jt] = __builtin_amdgcn_mfma_f32_16x16x32_bf16(A2l[jt][kt], B2h_, acc2[jt], 0, 0, 0);
            }
        }

        // scores: PReLU + W3-dot in-lane, reduce over G
        float sv = 0.f;
        #pragma unroll
        for (int jt = 0; jt < 2; ++jt)
            #pragma unroll
            for (int r = 0; r < 4; ++r) {
                float v = acc2[jt][r];
                v = fmaxf(v, 0.f) + a2 * fminf(v, 0.f);
                sv = fmaf(v, w3f[jt * 16 + 4 * G + r], sv);
            }
        sv += __shfl_xor(sv, 16, 64);
        sv += __shfl_xor(sv, 32, 64);
        int srow = st * 16 + c;
        if ((tid & 48) == 0 && srow < NS) scf[srow] = sv + b3;
    }
    __syncthreads();

    // ---------- decay + mask + softmax ----------
    float scval = -INFINITY;
    if (tid < NS) {
        if (kmask[(size_t)b * NS + tid] != 0)
            scval = scf[tid] * expf(0.1f * (float)(tid - (NS - 1)));
    }
    const int wid = tid >> 6, lane = tid & 63;
    float mx = scval;
    #pragma unroll
    for (int o = 32; o > 0; o >>= 1) mx = fmaxf(mx, __shfl_xor(mx, o, 64));
    if (lane == 0) wred[wid] = mx;
    __syncthreads();
    float M = fmaxf(fmaxf(wred[0], wred[1]), fmaxf(wred[2], wred[3]));
    float e = (M > -INFINITY) ? expf(scval - M) : 0.f;
    float ssum = e;
    #pragma unroll
    for (int o = 32; o > 0; o >>= 1) ssum += __shfl_xor(ssum, o, 64);
    if (lane == 0) wred[4 + wid] = ssum;
    __syncthreads();
    float SUM = wred[4] + wred[5] + wred[6] + wred[7];
    float wv_ = (SUM > 0.f) ? (e / SUM) : 0.f;
    if (tid < NS) {
        wbf[tid] = wv_;
        out[(size_t)NB * ND + (size_t)b * NS + tid] = wv_;
    }
    __syncthreads();

    // ---------- pass 2: weighted_sum = w @ keys ----------
    {
        const int d = tid & 127, half = tid >> 7;
        const float* kp = keys + ((size_t)b * NS + half * 100) * ND + d;
        float pacc = 0.f;
        #pragma unroll 5
        for (int i = 0; i < 100; ++i)
            pacc = fmaf(wbf[half * 100 + i], kp[(size_t)i * ND], pacc);
        bpf[half * 128 + d] = pacc;
    }
    __syncthreads();
    if (tid < 128)
        out[(size_t)b * ND + tid] = bpf[tid] + bpf[128 + tid];
}

extern "C" void kernel_launch(void* const* d_in, const int* in_sizes, int n_in,
                              void* d_out, int out_size, void* d_ws, size_t ws_size,
                              hipStream_t stream) {
    (void)in_sizes; (void)n_in; (void)d_ws; (void)ws_size; (void)out_size;
    const float* query = (const float*)d_in[0];
    const float* keys  = (const float*)d_in[1];
    const int*   kmask = (const int*)d_in[2];
    const float* W1 = (const float*)d_in[3];
    const float* b1 = (const float*)d_in[4];
    const float* a1 = (const float*)d_in[5];
    const float* W2 = (const float*)d_in[6];
    const float* b2 = (const float*)d_in[7];
    const float* a2 = (const float*)d_in[8];
    const float* W3 = (const float*)d_in[9];
    const float* b3 = (const float*)d_in[10];
    float* out = (float*)d_out;

    hipLaunchKernelGGL(tdra_main, dim3(NB), dim3(256), 0, stream,
                       query, keys, kmask, W1, b1, a1, W2, b2, a2, W3, b3, out);
}

// Round 6
// 77.364 us; speedup vs baseline: 3.4365x; 1.0850x over previous
//
#include <hip/hip_runtime.h>
#include <math.h>

#define NB 2048
#define NS 200
#define ND 128

typedef __attribute__((ext_vector_type(8))) short bf16x8;
typedef __attribute__((ext_vector_type(4))) float f32x4;
typedef __attribute__((ext_vector_type(4))) unsigned short u16x4;

// LDS layout (u32 units)
#define U_W1HI  0                  // 64 x 136 u16 = 4352 u32 (stride 136 u16 = 17x16B)
#define U_W1LO  4352               // 4352 u32
#define U_Q     8704               // 128 f32
#define U_BIAS  8832               // 64 f32
#define U_B2    8896               // 32 f32
#define U_W3    8928               // 32 f32
#define U_SC    8960               // 208 f32
#define U_WB    9168               // 208 f32
#define U_WRED  9376               // 8 f32
#define U_BP    9384               // 260 f32
#define U_TOTAL 9644               // 38576 B -> 4 blocks/CU

extern "C" __global__ void __launch_bounds__(256, 4)
tdra_main(const float* __restrict__ query,
          const float* __restrict__ keys,
          const int*   __restrict__ kmask,
          const float* __restrict__ W1,
          const float* __restrict__ b1,
          const float* __restrict__ a1p,
          const float* __restrict__ W2,
          const float* __restrict__ b2,
          const float* __restrict__ a2p,
          const float* __restrict__ W3,
          const float* __restrict__ b3p,
          float* __restrict__ out)
{
    __shared__ __align__(16) unsigned int smem[U_TOTAL];
    unsigned short* W1hi = (unsigned short*)(smem + U_W1HI);
    unsigned short* W1lo = (unsigned short*)(smem + U_W1LO);
    float* qf    = (float*)(smem + U_Q);
    float* biasE = (float*)(smem + U_BIAS);
    float* b2f   = (float*)(smem + U_B2);
    float* w3f   = (float*)(smem + U_W3);
    float* scf   = (float*)(smem + U_SC);
    float* wbf   = (float*)(smem + U_WB);
    float* wred  = (float*)(smem + U_WRED);
    float* bpf   = (float*)(smem + U_BP);

    const int tid = threadIdx.x;
    const int b   = blockIdx.x;
    const float a1 = a1p[0];
    const float a2 = a2p[0];
    const float b3 = b3p[0];

    const int wv = tid >> 6;
    const int c  = tid & 15;
    const int G  = (tid >> 4) & 3;

    // ---------- Phase 0a: q, b2, W3 staging ----------
    if (tid < 32) {
        float4 qv = *(const float4*)(query + (size_t)b * ND + tid * 4);
        *(float4*)(qf + tid * 4) = qv;
    } else if (tid < 64) {
        b2f[tid - 32] = b2[tid - 32];
    } else if (tid < 96) {
        w3f[tid - 64] = W3[tid - 64];
    }

    // A2 = W2^T fragments straight from global (st-invariant, L2-hit)
    bf16x8 A2h[2][2], A2l[2][2];
    #pragma unroll
    for (int jt = 0; jt < 2; ++jt)
        #pragma unroll
        for (int kt = 0; kt < 2; ++kt)
            #pragma unroll
            for (int e = 0; e < 8; ++e) {
                float x = W2[(kt * 32 + 8 * G + e) * 32 + jt * 16 + c];
                unsigned int u  = __float_as_uint(x);
                unsigned int hb = u & 0xFFFF0000u;
                float lof = x - __uint_as_float(hb);
                A2h[jt][kt][e] = (short)(u >> 16);
                A2l[jt][kt][e] = (short)(__float_as_uint(lof) >> 16);
            }
    __syncthreads();

    // ---------- Phase 0b: W1 planes = split(W1a+W1d+q*W1c); bias partials ----
    {
        int h = tid & 63, dg = tid >> 6;       // wave dg handles dblk dg*8..dg*8+7
        #pragma unroll 2
        for (int i = 0; i < 8; ++i) {
            int dblk = dg * 8 + i;
            u16x4 hi4, lo4;
            #pragma unroll
            for (int jj = 0; jj < 4; ++jj) {
                int d = dblk * 4 + jj;
                float qd = qf[d];
                float va = W1[d * 64 + h];
                float vc = W1[16384 + d * 64 + h];
                float vd = W1[24576 + d * 64 + h];
                float x  = va + vd + qd * vc;
                unsigned int u  = __float_as_uint(x);
                unsigned int hb = u & 0xFFFF0000u;
                float lof = x - __uint_as_float(hb);
                hi4[jj] = (unsigned short)(u >> 16);
                lo4[jj] = (unsigned short)(__float_as_uint(lof) >> 16);
            }
            *(u16x4*)(W1hi + h * 136 + dblk * 4) = hi4;
            *(u16x4*)(W1lo + h * 136 + dblk * 4) = lo4;
        }
        // bias partials: q @ (W1b - W1d)
        int qt = dg;
        const float* pb = W1 + (size_t)(128 + qt * 32) * 64 + h;
        const float* pd = W1 + (size_t)(384 + qt * 32) * 64 + h;
        float p = 0.f;
        #pragma unroll 8
        for (int i = 0; i < 32; ++i)
            p = fmaf(qf[qt * 32 + i], pb[i * 64] - pd[i * 64], p);
        bpf[qt * 65 + h] = p;
    }
    __syncthreads();
    if (tid < 64)
        biasE[tid] = b1[tid] + bpf[tid] + bpf[65 + tid] + bpf[130 + tid] + bpf[195 + tid];
    __syncthreads();

    // ---------- Main: wave wv owns s-tiles st = wv, wv+4, wv+8, (wv+12) ------
    #pragma unroll 1
    for (int st = wv; st < 13; st += 4) {
        int row = st * 16 + c; if (row > 199) row = 199;
        const float* kp = keys + ((size_t)b * NS + row) * ND + 8 * G;

        // keys f32 -> B1 hi/lo frags (staggered to cap VGPR)
        bf16x8 B1h[4], B1l[4];
        #pragma unroll
        for (int half = 0; half < 2; ++half) {
            float4 xs[4];
            #pragma unroll
            for (int q_ = 0; q_ < 2; ++q_) {
                xs[2 * q_]     = *(const float4*)(kp + (2 * half + q_) * 32);
                xs[2 * q_ + 1] = *(const float4*)(kp + (2 * half + q_) * 32 + 4);
            }
            #pragma unroll
            for (int q_ = 0; q_ < 2; ++q_) {
                int dt = 2 * half + q_;
                float t_[8] = {xs[2*q_].x, xs[2*q_].y, xs[2*q_].z, xs[2*q_].w,
                               xs[2*q_+1].x, xs[2*q_+1].y, xs[2*q_+1].z, xs[2*q_+1].w};
                #pragma unroll
                for (int e = 0; e < 8; ++e) {
                    unsigned int u  = __float_as_uint(t_[e]);
                    unsigned int hb = u & 0xFFFF0000u;
                    float lof = t_[e] - __uint_as_float(hb);
                    B1h[dt][e] = (short)(u >> 16);
                    B1l[dt][e] = (short)(__float_as_uint(lof) >> 16);
                }
            }
        }

        // GEMM1': acc1[ht] = bias + W1eff^T x K^T
        f32x4 acc1[4];
        #pragma unroll
        for (int ht = 0; ht < 4; ++ht)
            acc1[ht] = *(const f32x4*)(biasE + 16 * ht + 4 * G);
        #pragma unroll
        for (int dt = 0; dt < 4; ++dt) {
            #pragma unroll
            for (int ht = 0; ht < 4; ++ht) {
                int idx = (16 * ht + c) * 136 + 32 * dt + 8 * G;
                bf16x8 A1h = *(const bf16x8*)(W1hi + idx);
                bf16x8 A1l = *(const bf16x8*)(W1lo + idx);
                acc1[ht] = __builtin_amdgcn_mfma_f32_16x16x32_bf16(A1h, B1h[dt], acc1[ht], 0, 0, 0);
                acc1[ht] = __builtin_amdgcn_mfma_f32_16x16x32_bf16(A1h, B1l[dt], acc1[ht], 0, 0, 0);
                acc1[ht] = __builtin_amdgcn_mfma_f32_16x16x32_bf16(A1l, B1h[dt], acc1[ht], 0, 0, 0);
            }
        }

        // PReLU -> packed hi|lo h1
        unsigned int p[4][4];
        #pragma unroll
        for (int ht = 0; ht < 4; ++ht)
            #pragma unroll
            for (int r = 0; r < 4; ++r) {
                float v = acc1[ht][r];
                v = fmaxf(v, 0.f) + a1 * fminf(v, 0.f);
                unsigned int u  = __float_as_uint(v);
                unsigned int hb = u & 0xFFFF0000u;
                float lof = v - __uint_as_float(hb);
                p[ht][r] = (u >> 16) | (__float_as_uint(lof) & 0xFFFF0000u);
            }

        // GEMM2': shfl-transpose h1 into B2 frags; acc2 init with b2
        f32x4 acc2[2];
        acc2[0] = *(const f32x4*)(b2f + 4 * G);
        acc2[1] = *(const f32x4*)(b2f + 16 + 4 * G);
        const int srcbase = ((tid & 16) ? 32 : 0) + c;
        #pragma unroll
        for (int kt = 0; kt < 2; ++kt) {
            unsigned int q[8];
            #pragma unroll
            for (int half = 0; half < 2; ++half) {
                int src = srcbase + half * 16;
                #pragma unroll
                for (int r = 0; r < 4; ++r) {
                    unsigned int v0 = (unsigned int)__shfl((int)p[2 * kt][r], src, 64);
                    unsigned int v1 = (unsigned int)__shfl((int)p[2 * kt + 1][r], src, 64);
                    q[half * 4 + r] = (tid & 32) ? v1 : v0;
                }
            }
            bf16x8 B2h_, B2l_;
            #pragma unroll
            for (int e = 0; e < 8; ++e) {
                B2h_[e] = (short)(q[e] & 0xFFFFu);
                B2l_[e] = (short)(q[e] >> 16);
            }
            #pragma unroll
            for (int jt = 0; jt < 2; ++jt) {
                acc2[jt] = __builtin_amdgcn_mfma_f32_16x16x32_bf16(A2h[jt][kt], B2h_, acc2[jt], 0, 0, 0);
                acc2[jt] = __builtin_amdgcn_mfma_f32_16x16x32_bf16(A2h[jt][kt], B2l_, acc2[jt], 0, 0, 0);
                acc2[jt] = __builtin_amdgcn_mfma_f32_16x16x32_bf16(A2l[jt][kt], B2h_, acc2[jt], 0, 0, 0);
            }
        }

        // scores: PReLU + W3-dot in-lane, reduce over G
        float sv = 0.f;
        #pragma unroll
        for (int jt = 0; jt < 2; ++jt)
            #pragma unroll
            for (int r = 0; r < 4; ++r) {
                float v = acc2[jt][r];
                v = fmaxf(v, 0.f) + a2 * fminf(v, 0.f);
                sv = fmaf(v, w3f[jt * 16 + 4 * G + r], sv);
            }
        sv += __shfl_xor(sv, 16, 64);
        sv += __shfl_xor(sv, 32, 64);
        int srow = st * 16 + c;
        if ((tid & 48) == 0 && srow < NS) scf[srow] = sv + b3;
    }
    __syncthreads();

    // ---------- decay + mask + softmax ----------
    float scval = -INFINITY;
    if (tid < NS) {
        if (kmask[(size_t)b * NS + tid] != 0)
            scval = scf[tid] * expf(0.1f * (float)(tid - (NS - 1)));
    }
    const int wid = tid >> 6, lane = tid & 63;
    float mx = scval;
    #pragma unroll
    for (int o = 32; o > 0; o >>= 1) mx = fmaxf(mx, __shfl_xor(mx, o, 64));
    if (lane == 0) wred[wid] = mx;
    __syncthreads();
    float M = fmaxf(fmaxf(wred[0], wred[1]), fmaxf(wred[2], wred[3]));
    float e = (M > -INFINITY) ? expf(scval - M) : 0.f;
    float ssum = e;
    #pragma unroll
    for (int o = 32; o > 0; o >>= 1) ssum += __shfl_xor(ssum, o, 64);
    if (lane == 0) wred[4 + wid] = ssum;
    __syncthreads();
    float SUM = wred[4] + wred[5] + wred[6] + wred[7];
    float wv_ = (SUM > 0.f) ? (e / SUM) : 0.f;
    if (tid < NS) {
        wbf[tid] = wv_;
        out[(size_t)NB * ND + (size_t)b * NS + tid] = wv_;
    }
    __syncthreads();

    // ---------- pass 2: weighted_sum = w @ keys ----------
    {
        const int d = tid & 127, half = tid >> 7;
        const float* kp = keys + ((size_t)b * NS + half * 100) * ND + d;
        float pacc = 0.f;
        #pragma unroll 5
        for (int i = 0; i < 100; ++i)
            pacc = fmaf(wbf[half * 100 + i], kp[(size_t)i * ND], pacc);
        bpf[half * 128 + d] = pacc;
    }
    __syncthreads();
    if (tid < 128)
        out[(size_t)b * ND + tid] = bpf[tid] + bpf[128 + tid];
}

extern "C" void kernel_launch(void* const* d_in, const int* in_sizes, int n_in,
                              void* d_out, int out_size, void* d_ws, size_t ws_size,
                              hipStream_t stream) {
    (void)in_sizes; (void)n_in; (void)d_ws; (void)ws_size; (void)out_size;
    const float* query = (const float*)d_in[0];
    const float* keys  = (const float*)d_in[1];
    const int*   kmask = (const int*)d_in[2];
    const float* W1 = (const float*)d_in[3];
    const float* b1 = (const float*)d_in[4];
    const float* a1 = (const float*)d_in[5];
    const float* W2 = (const float*)d_in[6];
    const float* b2 = (const float*)d_in[7];
    const float* a2 = (const float*)d_in[8];
    const float* W3 = (const float*)d_in[9];
    const float* b3 = (const float*)d_in[10];
    float* out = (float*)d_out;

    hipLaunchKernelGGL(tdra_main, dim3(NB), dim3(256), 0, stream,
                       query, keys, kmask, W1, b1, a1, W2, b2, a2, W3, b3, out);
}